// Round 7
// baseline (81.635 us; speedup 1.0000x reference)
//
#include <hip/hip_runtime.h>

// CharacteristicLineEncoder: B=4096, DIM=3, L=300, S=60, P=5, E=128
// out[b,s,e] = sum_p W_lr[s,p]*relu(W_le[e,:]·x[b,:,5s+p] + b_le[e]) + b_lr[s]
//            + relu( sum_l W_gn[l]*relu(W_ge[e,:]·x[b,:,l] + b_ge[e]) + b_gn )
//
// 384 threads = 3 balanced L-thirds x 128 e-lanes; third q owns regions
// s=20q..20q+19 (25 quads). Fused single sweep; la[20]+4 global accs in
// registers (static indexing). ALL l-indexed data (x, W_gn, W_lr) staged in
// LDS and read as broadcast ds_read_b128 (5 per quad) — no VMEM and no
// scalarization dependence in the hot loop (R6 lesson: q-dependent weight
// indices defeat s_load). Natural register allocation — NO min-waves arg
// (R4/R5 lesson: it forces spills).

#define Bv 4096
#define Sv 60
#define Ev 128

#define RELU(v) fmaxf((v), 0.0f)

__global__ __launch_bounds__(384) void cle_kernel(
    const float* __restrict__ x,     // [B,3,300]
    const float* __restrict__ W_le,  // [E,3]
    const float* __restrict__ b_le,  // [E]
    const float* __restrict__ W_lr,  // [300]
    const float* __restrict__ b_lr,  // [S]
    const float* __restrict__ W_ge,  // [E,3]
    const float* __restrict__ b_ge,  // [E]
    const float* __restrict__ W_gn,  // [300]
    const float* __restrict__ b_gn,  // [1]
    float* __restrict__ out)         // [B,S,E]
{
    const int tid = threadIdx.x;
    const int e = tid & 127;     // embedding channel
    const int q = tid >> 7;      // L-third 0..2 (wave-uniform)
    const int b = blockIdx.x;

    __shared__ __align__(16) float4 sx4[225];   // x[b]: channel c, quad j at [c*75+j]
    __shared__ __align__(16) float4 swgn4[75];  // W_gn quads
    __shared__ __align__(16) float4 swlr4[75];  // W_lr quads
    __shared__ __align__(16) float  sblr[60];   // b_lr
    __shared__ float sg[384];                   // global-branch partials

    // ---- stage (coalesced float4) ----
    if (tid < 225)       sx4[tid]         = ((const float4*)(x + (size_t)b * 900))[tid];
    else if (tid < 300)  swgn4[tid - 225] = ((const float4*)W_gn)[tid - 225];
    else if (tid < 375)  swlr4[tid - 300] = ((const float4*)W_lr)[tid - 300];
    if (tid < 15)        ((float4*)sblr)[tid] = ((const float4*)b_lr)[tid];

    // per-lane (per-e) weights
    const float wl0 = W_le[e * 3 + 0], wl1 = W_le[e * 3 + 1], wl2 = W_le[e * 3 + 2];
    const float bl  = b_le[e];
    const float wg0 = W_ge[e * 3 + 0], wg1 = W_ge[e * 3 + 1], wg2 = W_ge[e * 3 + 2];
    const float bg  = b_ge[e];
    const float bgn = b_gn[0];

    __syncthreads();

    const int qb = q * 25;   // quad base for this third (l base = 100q)

    float g0 = 0.f, g1 = 0.f, g2 = 0.f, g3 = 0.f;
    float la[20];
#pragma unroll
    for (int i = 0; i < 20; ++i) la[i] = 0.0f;

#define GEq(cmp) RELU(fmaf(wg2, c2.cmp, fmaf(wg1, c1.cmp, fmaf(wg0, c0.cmp, bg))))
#define LEq(cmp) RELU(fmaf(wl2, c2.cmp, fmaf(wl1, c1.cmp, fmaf(wl0, c0.cmp, bl))))
#define DOQ(qi, A0, A1, A2, A3)                                            \
    {                                                                      \
        const int qq = q0 + (qi);                                          \
        const float4 c0 = sx4[qq], c1 = sx4[75 + qq], c2 = sx4[150 + qq];  \
        const float4 w4 = swgn4[qq], v4 = swlr4[qq];                       \
        g0 = fmaf(w4.x, GEq(x), g0);                                       \
        g1 = fmaf(w4.y, GEq(y), g1);                                       \
        g2 = fmaf(w4.z, GEq(z), g2);                                       \
        g3 = fmaf(w4.w, GEq(w), g3);                                       \
        A0 = fmaf(v4.x, LEq(x), A0);                                       \
        A1 = fmaf(v4.y, LEq(y), A1);                                       \
        A2 = fmaf(v4.z, LEq(z), A2);                                       \
        A3 = fmaf(v4.w, LEq(w), A3);                                       \
    }

    // 5 groups of 4 regions each (group = 20 l = 5 quads), all thirds balanced
#pragma unroll
    for (int g = 0; g < 5; ++g) {
        const int q0 = qb + g * 5;
        const int r = g << 2;
        // element t = 4*qi + component (l = 100q + 20g + t), region += t/5
        DOQ(0, la[r + 0], la[r + 0], la[r + 0], la[r + 0])  // t 0..3
        DOQ(1, la[r + 0], la[r + 1], la[r + 1], la[r + 1])  // t 4..7
        DOQ(2, la[r + 1], la[r + 1], la[r + 2], la[r + 2])  // t 8..11
        DOQ(3, la[r + 2], la[r + 2], la[r + 2], la[r + 3])  // t 12..15
        DOQ(4, la[r + 3], la[r + 3], la[r + 3], la[r + 3])  // t 16..19
    }

    // combine global-branch partials across the 3 thirds
    sg[tid] = (g0 + g1) + (g2 + g3);
    __syncthreads();
    const float gf = RELU((sg[e] + sg[128 + e]) + sg[256 + e] + bgn);

    // stores: third q writes s = 20q + 4g + j  (coalesced per 128-lane group)
    float* ob = out + (size_t)b * (Sv * Ev) + (size_t)(q * 20) * Ev + e;
#pragma unroll
    for (int g = 0; g < 5; ++g) {
        const int r = g << 2;
        const int s0 = q * 20 + (g << 2);
        float* og = ob + (size_t)(g << 2) * Ev;
        og[0 * Ev] = (la[r + 0] + gf) + sblr[s0 + 0];
        og[1 * Ev] = (la[r + 1] + gf) + sblr[s0 + 1];
        og[2 * Ev] = (la[r + 2] + gf) + sblr[s0 + 2];
        og[3 * Ev] = (la[r + 3] + gf) + sblr[s0 + 3];
    }
}

extern "C" void kernel_launch(void* const* d_in, const int* in_sizes, int n_in,
                              void* d_out, int out_size, void* d_ws, size_t ws_size,
                              hipStream_t stream) {
    const float* x    = (const float*)d_in[0];
    const float* W_le = (const float*)d_in[1];
    const float* b_le = (const float*)d_in[2];
    const float* W_lr = (const float*)d_in[3];
    const float* b_lr = (const float*)d_in[4];
    const float* W_ge = (const float*)d_in[5];
    const float* b_ge = (const float*)d_in[6];
    const float* W_gn = (const float*)d_in[7];
    const float* b_gn = (const float*)d_in[8];
    float* out = (float*)d_out;

    cle_kernel<<<Bv, 384, 0, stream>>>(x, W_le, b_le, W_lr, b_lr,
                                       W_ge, b_ge, W_gn, b_gn, out);
}

// Round 8
// 46.522 us; speedup vs baseline: 1.7548x; 1.7548x over previous
//
#include <hip/hip_runtime.h>

// CharacteristicLineEncoder: B=4096, DIM=3, L=300, S=60, P=5, E=128
// out[b,s,e] = sum_p W_lr[s,p]*relu(W_le[e,:]·x[b,:,5s+p] + b_le[e]) + b_lr[s]
//            + relu( sum_l W_gn[l]*relu(W_ge[e,:]·x[b,:,l] + b_ge[e]) + b_gn )
//
// One wave (64 lanes) per batch element; each lane owns e-pair {2*lane,2*lane+1}.
// This halves per-CU broadcast-LDS instructions vs one-e-per-lane (the R2/R3
// 51us plateau was per-wave ds_read issue cost). No inter-wave barriers; all
// weight indices are uniform (loop var + constants) -> scalar s_load path
// (R6 lesson: tid-derived indices defeat scalarization). Two sweeps over
// LDS-staged x: global branch first (gf), then local + fused store (dwordx2).
// Natural register allocation — no min-waves arg (R4/R5 spill lesson).

#define RELU(v) fmaxf((v), 0.0f)

__global__ __launch_bounds__(64) void cle_kernel(
    const float* __restrict__ x,     // [B,3,300]
    const float* __restrict__ W_le,  // [E,3]
    const float* __restrict__ b_le,  // [E]
    const float* __restrict__ W_lr,  // [300]
    const float* __restrict__ b_lr,  // [60]
    const float* __restrict__ W_ge,  // [E,3]
    const float* __restrict__ b_ge,  // [E]
    const float* __restrict__ W_gn,  // [300]
    const float* __restrict__ b_gn,  // [1]
    float* __restrict__ out)         // [B,60,128]
{
    const int lane = threadIdx.x;    // 0..63
    const int b = blockIdx.x;
    const int e0 = lane << 1;        // this lane's e-pair: e0, e0+1

    __shared__ __align__(16) float4 sx4[225];   // x[b]: channel c, quad j at [c*75+j]

    // ---- stage x[b] (3.6 KB) with coalesced float4 loads ----
    {
        const float4* xg4 = (const float4*)(x + (size_t)b * 900);
        sx4[lane]       = xg4[lane];
        sx4[lane + 64]  = xg4[lane + 64];
        sx4[lane + 128] = xg4[lane + 128];
        if (lane < 33) sx4[lane + 192] = xg4[lane + 192];
    }

    // global-branch per-e weights (two channels per lane)
    const float wg00 = W_ge[e0 * 3 + 0], wg01 = W_ge[e0 * 3 + 1], wg02 = W_ge[e0 * 3 + 2];
    const float wg10 = W_ge[e0 * 3 + 3], wg11 = W_ge[e0 * 3 + 4], wg12 = W_ge[e0 * 3 + 5];
    const float bg0 = b_ge[e0], bg1 = b_ge[e0 + 1];
    const float bgn = b_gn[0];

    __syncthreads();

    // ---- sweep 1: global branch over all 300 l ----
    float ga0 = 0.f, ga1 = 0.f, ga2 = 0.f, ga3 = 0.f;   // e0, 4 chains
    float gb0 = 0.f, gb1 = 0.f, gb2 = 0.f, gb3 = 0.f;   // e1
#define GE0(cmp) RELU(fmaf(wg02, c2.cmp, fmaf(wg01, c1.cmp, fmaf(wg00, c0.cmp, bg0))))
#define GE1(cmp) RELU(fmaf(wg12, c2.cmp, fmaf(wg11, c1.cmp, fmaf(wg10, c0.cmp, bg1))))
    for (int g = 0; g < 15; ++g) {           // g is wave-uniform (loop var)
        const int q0 = g * 5;
#pragma unroll
        for (int qi = 0; qi < 5; ++qi) {
            const int qq = q0 + qi;
            const int l4 = qq * 4;           // uniform -> W_gn scalarizes
            const float4 c0 = sx4[qq], c1 = sx4[75 + qq], c2 = sx4[150 + qq];
            ga0 = fmaf(W_gn[l4 + 0], GE0(x), ga0);
            gb0 = fmaf(W_gn[l4 + 0], GE1(x), gb0);
            ga1 = fmaf(W_gn[l4 + 1], GE0(y), ga1);
            gb1 = fmaf(W_gn[l4 + 1], GE1(y), gb1);
            ga2 = fmaf(W_gn[l4 + 2], GE0(z), ga2);
            gb2 = fmaf(W_gn[l4 + 2], GE1(z), gb2);
            ga3 = fmaf(W_gn[l4 + 3], GE0(w), ga3);
            gb3 = fmaf(W_gn[l4 + 3], GE1(w), gb3);
        }
    }
    const float gf0 = RELU(((ga0 + ga1) + (ga2 + ga3)) + bgn);
    const float gf1 = RELU(((gb0 + gb1) + (gb2 + gb3)) + bgn);

    // local-branch per-e weights (loaded after sweep 1 to lower peak pressure)
    const float wl00 = W_le[e0 * 3 + 0], wl01 = W_le[e0 * 3 + 1], wl02 = W_le[e0 * 3 + 2];
    const float wl10 = W_le[e0 * 3 + 3], wl11 = W_le[e0 * 3 + 4], wl12 = W_le[e0 * 3 + 5];
    const float bl0 = b_le[e0], bl1 = b_le[e0 + 1];

    // ---- sweep 2: local branch, 4 regions (20 l = 5 quads) per group ----
    float2* ob2 = (float2*)(out + (size_t)b * (60 * 128)) + lane;   // + s*64

#define LE0(cmp) RELU(fmaf(wl02, c2.cmp, fmaf(wl01, c1.cmp, fmaf(wl00, c0.cmp, bl0))))
#define LE1(cmp) RELU(fmaf(wl12, c2.cmp, fmaf(wl11, c1.cmp, fmaf(wl10, c0.cmp, bl1))))
#define DOQ(qi, R0, R1, R2, R3)                                                \
    {                                                                          \
        const int qq = q0 + (qi);                                              \
        const int lw = qq * 4;            /* uniform -> W_lr scalarizes */     \
        const float4 c0 = sx4[qq], c1 = sx4[75 + qq], c2 = sx4[150 + qq];      \
        a0##R0 = fmaf(W_lr[lw + 0], LE0(x), a0##R0);                           \
        a1##R0 = fmaf(W_lr[lw + 0], LE1(x), a1##R0);                           \
        a0##R1 = fmaf(W_lr[lw + 1], LE0(y), a0##R1);                           \
        a1##R1 = fmaf(W_lr[lw + 1], LE1(y), a1##R1);                           \
        a0##R2 = fmaf(W_lr[lw + 2], LE0(z), a0##R2);                           \
        a1##R2 = fmaf(W_lr[lw + 2], LE1(z), a1##R2);                           \
        a0##R3 = fmaf(W_lr[lw + 3], LE0(w), a0##R3);                           \
        a1##R3 = fmaf(W_lr[lw + 3], LE1(w), a1##R3);                           \
    }

    for (int g = 0; g < 15; ++g) {           // uniform
        const int q0 = g * 5;
        float a00 = 0.f, a01 = 0.f, a02 = 0.f, a03 = 0.f;   // e0, regions 4g..4g+3
        float a10 = 0.f, a11 = 0.f, a12 = 0.f, a13 = 0.f;   // e1
        // element t = 4*qi + component (l = 20g + t), region = 4g + t/5
        DOQ(0, 0, 0, 0, 0)   // t 0..3
        DOQ(1, 0, 1, 1, 1)   // t 4..7
        DOQ(2, 1, 1, 2, 2)   // t 8..11
        DOQ(3, 2, 2, 2, 3)   // t 12..15
        DOQ(4, 3, 3, 3, 3)   // t 16..19

        const int s0 = g * 4;                // b_lr[s] stays scalar
        ob2[(s0 + 0) * 64] = make_float2(a00 + gf0 + b_lr[s0 + 0], a10 + gf1 + b_lr[s0 + 0]);
        ob2[(s0 + 1) * 64] = make_float2(a01 + gf0 + b_lr[s0 + 1], a11 + gf1 + b_lr[s0 + 1]);
        ob2[(s0 + 2) * 64] = make_float2(a02 + gf0 + b_lr[s0 + 2], a12 + gf1 + b_lr[s0 + 2]);
        ob2[(s0 + 3) * 64] = make_float2(a03 + gf0 + b_lr[s0 + 3], a13 + gf1 + b_lr[s0 + 3]);
    }
}

extern "C" void kernel_launch(void* const* d_in, const int* in_sizes, int n_in,
                              void* d_out, int out_size, void* d_ws, size_t ws_size,
                              hipStream_t stream) {
    const float* x    = (const float*)d_in[0];
    const float* W_le = (const float*)d_in[1];
    const float* b_le = (const float*)d_in[2];
    const float* W_lr = (const float*)d_in[3];
    const float* b_lr = (const float*)d_in[4];
    const float* W_ge = (const float*)d_in[5];
    const float* b_ge = (const float*)d_in[6];
    const float* W_gn = (const float*)d_in[7];
    const float* b_gn = (const float*)d_in[8];
    float* out = (float*)d_out;

    cle_kernel<<<4096, 64, 0, stream>>>(x, W_le, b_le, W_lr, b_lr,
                                        W_ge, b_ge, W_gn, b_gn, out);
}

// Round 9
// 45.604 us; speedup vs baseline: 1.7901x; 1.0201x over previous
//
#include <hip/hip_runtime.h>

// CharacteristicLineEncoder: B=4096, DIM=3, L=300, S=60, P=5, E=128
// out[b,s,e] = sum_p W_lr[s,p]*relu(W_le[e,:]·x[b,:,5s+p] + b_le[e]) + b_lr[s]
//            + relu( sum_l W_gn[l]*relu(W_ge[e,:]·x[b,:,l] + b_ge[e]) + b_gn )
//
// 256 threads = 4 waves per batch element; every wave uses e-pair lanes
// (lane owns e={2*lane,2*lane+1}, so ONE wave covers all 128 e -> minimum
// broadcast-LDS instructions, the R8 lesson). Wave w owns an L-quarter:
// sweep1 quads 20w.. (20/20/20/15), sweep2 regions 16w.. (16/16/16/12,
// quad-aligned). 4x shorter chains + ~32 waves/CU vs R8's 16 (R8 lesson:
// latency-bound at 4 waves/SIMD). wq passes through readfirstlane so all
// weight indices stay provably wave-uniform -> s_load path (R6 lesson).
// Natural register allocation — no min-waves arg (R4/R5 spill lesson).

#define RELU(v) fmaxf((v), 0.0f)

__global__ __launch_bounds__(256) void cle_kernel(
    const float* __restrict__ x,     // [B,3,300]
    const float* __restrict__ W_le,  // [E,3]
    const float* __restrict__ b_le,  // [E]
    const float* __restrict__ W_lr,  // [300]
    const float* __restrict__ b_lr,  // [60]
    const float* __restrict__ W_ge,  // [E,3]
    const float* __restrict__ b_ge,  // [E]
    const float* __restrict__ W_gn,  // [300]
    const float* __restrict__ b_gn,  // [1]
    float* __restrict__ out)         // [B,60,128]
{
    const int tid  = threadIdx.x;
    const int lane = tid & 63;
    const int wq   = __builtin_amdgcn_readfirstlane(tid >> 6);  // wave 0..3, SGPR
    const int b    = blockIdx.x;
    const int e0   = lane << 1;      // this lane's e-pair

    __shared__ __align__(16) float4 sx4[225];  // x[b]: channel c, quad j at [c*75+j]
    __shared__ float2 sgp[4][64];              // per-wave global-branch partials

    // ---- stage x[b] (3.6 KB), coalesced float4 ----
    if (tid < 225) sx4[tid] = ((const float4*)(x + (size_t)b * 900))[tid];

    // per-lane (e-pair) weights
    const float wg00 = W_ge[e0 * 3 + 0], wg01 = W_ge[e0 * 3 + 1], wg02 = W_ge[e0 * 3 + 2];
    const float wg10 = W_ge[e0 * 3 + 3], wg11 = W_ge[e0 * 3 + 4], wg12 = W_ge[e0 * 3 + 5];
    const float bg0 = b_ge[e0], bg1 = b_ge[e0 + 1];
    const float wl00 = W_le[e0 * 3 + 0], wl01 = W_le[e0 * 3 + 1], wl02 = W_le[e0 * 3 + 2];
    const float wl10 = W_le[e0 * 3 + 3], wl11 = W_le[e0 * 3 + 4], wl12 = W_le[e0 * 3 + 5];
    const float bl0 = b_le[e0], bl1 = b_le[e0 + 1];
    const float bgn = b_gn[0];

    __syncthreads();

    // ---- sweep 1: global branch over this wave's quads ----
    float ga0 = 0.f, ga1 = 0.f, ga2 = 0.f, ga3 = 0.f;   // e0
    float gb0 = 0.f, gb1 = 0.f, gb2 = 0.f, gb3 = 0.f;   // e1
#define GE0(cmp) RELU(fmaf(wg02, c2.cmp, fmaf(wg01, c1.cmp, fmaf(wg00, c0.cmp, bg0))))
#define GE1(cmp) RELU(fmaf(wg12, c2.cmp, fmaf(wg11, c1.cmp, fmaf(wg10, c0.cmp, bg1))))
    {
        const int qb = wq * 20;
        const int nq = (wq < 3) ? 20 : 15;   // SGPR
        for (int g = 0; g < 4; ++g) {
            if (g * 5 < nq) {                // wave-uniform guard
#pragma unroll
                for (int qi = 0; qi < 5; ++qi) {
                    const int qq = qb + g * 5 + qi;
                    const int l4 = qq * 4;   // uniform -> W_gn scalarizes
                    const float4 c0 = sx4[qq], c1 = sx4[75 + qq], c2 = sx4[150 + qq];
                    ga0 = fmaf(W_gn[l4 + 0], GE0(x), ga0);
                    gb0 = fmaf(W_gn[l4 + 0], GE1(x), gb0);
                    ga1 = fmaf(W_gn[l4 + 1], GE0(y), ga1);
                    gb1 = fmaf(W_gn[l4 + 1], GE1(y), gb1);
                    ga2 = fmaf(W_gn[l4 + 2], GE0(z), ga2);
                    gb2 = fmaf(W_gn[l4 + 2], GE1(z), gb2);
                    ga3 = fmaf(W_gn[l4 + 3], GE0(w), ga3);
                    gb3 = fmaf(W_gn[l4 + 3], GE1(w), gb3);
                }
            }
        }
    }
    sgp[wq][lane] = make_float2((ga0 + ga1) + (ga2 + ga3), (gb0 + gb1) + (gb2 + gb3));
    __syncthreads();

    float gf0, gf1;
    {
        const float2 p0 = sgp[0][lane], p1 = sgp[1][lane];
        const float2 p2 = sgp[2][lane], p3 = sgp[3][lane];
        gf0 = RELU(((p0.x + p1.x) + (p2.x + p3.x)) + bgn);
        gf1 = RELU(((p0.y + p1.y) + (p2.y + p3.y)) + bgn);
    }

    // ---- sweep 2: local branch; wave wq owns regions 16wq.. (16/16/16/12) ----
    float2* ob2 = (float2*)(out + (size_t)b * (60 * 128)) + lane;   // + s*64

#define LE0(cmp) RELU(fmaf(wl02, c2.cmp, fmaf(wl01, c1.cmp, fmaf(wl00, c0.cmp, bl0))))
#define LE1(cmp) RELU(fmaf(wl12, c2.cmp, fmaf(wl11, c1.cmp, fmaf(wl10, c0.cmp, bl1))))
#define DOQ(qi, R0, R1, R2, R3)                                                \
    {                                                                          \
        const int qq = q0 + (qi);                                              \
        const int lw = qq * 4;            /* uniform -> W_lr scalarizes */     \
        const float4 c0 = sx4[qq], c1 = sx4[75 + qq], c2 = sx4[150 + qq];      \
        a0##R0 = fmaf(W_lr[lw + 0], LE0(x), a0##R0);                           \
        a1##R0 = fmaf(W_lr[lw + 0], LE1(x), a1##R0);                           \
        a0##R1 = fmaf(W_lr[lw + 1], LE0(y), a0##R1);                           \
        a1##R1 = fmaf(W_lr[lw + 1], LE1(y), a1##R1);                           \
        a0##R2 = fmaf(W_lr[lw + 2], LE0(z), a0##R2);                           \
        a1##R2 = fmaf(W_lr[lw + 2], LE1(z), a1##R2);                           \
        a0##R3 = fmaf(W_lr[lw + 3], LE0(w), a0##R3);                           \
        a1##R3 = fmaf(W_lr[lw + 3], LE1(w), a1##R3);                           \
    }

    {
        const int ng = (wq < 3) ? 4 : 3;     // SGPR: groups of 4 regions
        for (int g = 0; g < 4; ++g) {
            if (g < ng) {                    // wave-uniform guard
                const int q0 = wq * 20 + g * 5;
                float a00 = 0.f, a01 = 0.f, a02 = 0.f, a03 = 0.f;  // e0
                float a10 = 0.f, a11 = 0.f, a12 = 0.f, a13 = 0.f;  // e1
                // element t = 4*qi + comp (l = 80wq + 20g + t), region = t/5
                DOQ(0, 0, 0, 0, 0)   // t 0..3
                DOQ(1, 0, 1, 1, 1)   // t 4..7
                DOQ(2, 1, 1, 2, 2)   // t 8..11
                DOQ(3, 2, 2, 2, 3)   // t 12..15
                DOQ(4, 3, 3, 3, 3)   // t 16..19

                const int s0 = wq * 16 + g * 4;   // uniform -> b_lr scalar
                ob2[(s0 + 0) * 64] = make_float2(a00 + gf0 + b_lr[s0 + 0], a10 + gf1 + b_lr[s0 + 0]);
                ob2[(s0 + 1) * 64] = make_float2(a01 + gf0 + b_lr[s0 + 1], a11 + gf1 + b_lr[s0 + 1]);
                ob2[(s0 + 2) * 64] = make_float2(a02 + gf0 + b_lr[s0 + 2], a12 + gf1 + b_lr[s0 + 2]);
                ob2[(s0 + 3) * 64] = make_float2(a03 + gf0 + b_lr[s0 + 3], a13 + gf1 + b_lr[s0 + 3]);
            }
        }
    }
}

extern "C" void kernel_launch(void* const* d_in, const int* in_sizes, int n_in,
                              void* d_out, int out_size, void* d_ws, size_t ws_size,
                              hipStream_t stream) {
    const float* x    = (const float*)d_in[0];
    const float* W_le = (const float*)d_in[1];
    const float* b_le = (const float*)d_in[2];
    const float* W_lr = (const float*)d_in[3];
    const float* b_lr = (const float*)d_in[4];
    const float* W_ge = (const float*)d_in[5];
    const float* b_ge = (const float*)d_in[6];
    const float* W_gn = (const float*)d_in[7];
    const float* b_gn = (const float*)d_in[8];
    float* out = (float*)d_out;

    cle_kernel<<<4096, 256, 0, stream>>>(x, W_le, b_le, W_lr, b_lr,
                                         W_ge, b_ge, W_gn, b_gn, out);
}